// Round 1
// 1789.082 us; speedup vs baseline: 2.7132x; 2.7132x over previous
//
#include <hip/hip_runtime.h>

// RateRNN: u_{t+1} = clip(u + dt*du), du = (-u + f + r@W^T + bias + eta)*tau_inv
// Persistent kernel, 256 WGs x 256 threads (1 WG/CU resident).
//   WG g: bt-group bti=g>>6 (16 of 64 sequences), m-slice mi=g&63 (32 of 2048 units).
//   W-slice (32 x 2048) in registers as bf16 MFMA B-fragments (128 VGPR/thread).
//
// Fence-free sync protocol (this revision): ALL cross-WG data (rbuf, flags) moves
// with device-scope (sc1) accesses that execute at the coherent point (memory-side
// L3). No __threadfence / RELEASE fences -> no buffer_inv / L2-writeback per step,
// which was the dominant per-step cost (~19us/step, all pipes <2% busy).
//   - r stores: packed 2xbf16 -> one u32 __hip_atomic_store(RELAXED, AGENT)
//   - release:  s_waitcnt vmcnt(0) (stores acked at L3) + RELAXED flag store
//   - A-frag loads: inline-asm global_load_dwordx4 sc0 sc1 (16 issued in flight,
//     single vmcnt(0) + sched_barrier before MFMAs, per guide rule #18)
//   - u_hist/du_hist stores are normal cached stores issued AFTER the flag store
//     (off the notification critical path; drained by next iter's vmcnt anyway)
// Flag protocol unchanged: flags[g] = #r buffers produced. Iter t waits flags>=t+1
// (r_t ready AND everyone done reading r_{t-1}, which shares the buffer we write
// r_{t+1} into), produces r_{t+1}, sets flags=t+2.
//
// Per-thread cell remap vs prev rev: thread owns (bt = bt0+(tid>>4), n0 = m0+2*(tid&15),
// n0+1) so the r store is a single aligned dword and f/noise/hist are float2.

#define N_H     2048
#define N_EXC   1638
#define T_STEPS 256
#define BT_TOT  64   // B*TR

typedef __bf16 bf16_t;
typedef __attribute__((ext_vector_type(8))) __bf16 bf16x8;
typedef __attribute__((ext_vector_type(4))) float  f32x4;
typedef __attribute__((ext_vector_type(2))) float  f32x2;

__global__ __launch_bounds__(256, 1)
void rnn_persistent(const float* __restrict__ u0,
                    const float* __restrict__ fs,
                    const float* __restrict__ noise,
                    const float* __restrict__ Wrec,
                    const float* __restrict__ bias,
                    float* __restrict__ out,
                    bf16_t* __restrict__ rbuf,   // [2][64][2048] bf16
                    int* __restrict__ flags)     // [256]
{
    const int g    = blockIdx.x;
    const int bti  = g >> 6;          // 0..3
    const int mi   = g & 63;          // 0..63
    const int tid  = threadIdx.x;
    const int wave = tid >> 6;        // 0..3, owns K range [wave*512, +512)
    const int lane = tid & 63;
    const int l15  = lane & 15;
    const int quad = lane >> 4;

    const int bt0 = bti * 16;
    const int m0  = mi * 32;
    const int kw0 = wave * 512;

    float* u_hist  = out;                                   // 64*256*2048
    float* eta_out = out + (size_t)BT_TOT * T_STEPS * N_H;  // 64*2048
    float* du_hist = eta_out + (size_t)BT_TOT * N_H;        // 64*256*2048

    // ---- per-thread state: cells (bt, n0) and (bt, n0+1) ----
    const int row  = tid >> 4;            // bt - bt0, 0..15
    const int bt   = bt0 + row;
    const int nloc = (tid & 15) * 2;      // 0,2,..,30
    const int n0   = m0 + nloc;
    const int tile = nloc >> 4;           // which 16-col MFMA tile
    const int col  = nloc & 15;           // even
    const int srcl = (row >> 2) * 16 + col;
    const int reg  = row & 3;

    const f32x2 bv  = *(const f32x2*)(bias + n0);
    const float ti0 = (n0     < N_EXC) ? 50.0f : 100.0f;  // 1/0.02, 1/0.01
    const float ti1 = (n0 + 1 < N_EXC) ? 50.0f : 100.0f;

    f32x2 uv = *(const f32x2*)(u0 + (size_t)bt * N_H + n0);
    float uA = uv.x, uB = uv.y;

    // ---- produce r_0 into buffer 0 ASAP (device-scope store -> L3) ----
    {
      union { bf16_t h[2]; unsigned int w; } rp;
      rp.h[0] = (bf16_t)fmaxf(uA, 0.0f);
      rp.h[1] = (bf16_t)fmaxf(uB, 0.0f);
      __hip_atomic_store((unsigned int*)(rbuf + (size_t)bt * N_H + n0), rp.w,
                         __ATOMIC_RELAXED, __HIP_MEMORY_SCOPE_AGENT);
    }
    asm volatile("s_waitcnt vmcnt(0)" ::: "memory");  // r0 acked at coherent point
    __syncthreads();
    if (tid == 0)
      __hip_atomic_store(&flags[g], 1, __ATOMIC_RELAXED, __HIP_MEMORY_SCOPE_AGENT);

    // ---- W-slice into register B-fragments (overlaps other WGs' startup) ----
    // B-frag (16x16x32): lane holds B[k = quad*8+j][col = lane&15], j=0..7
    // B[k][col] = W[m0 + tl*16 + col][kw0 + kk*32 + k]
    bf16x8 Wf[16][2];
#pragma unroll
    for (int kk = 0; kk < 16; ++kk) {
#pragma unroll
      for (int tl = 0; tl < 2; ++tl) {
        const float* wp = Wrec + (size_t)(m0 + tl*16 + l15) * N_H
                               + (kw0 + kk*32 + quad*8);
        f32x4 w0 = *(const f32x4*)(wp);
        f32x4 w1 = *(const f32x4*)(wp + 4);
        bf16x8 v;
#pragma unroll
        for (int j = 0; j < 4; ++j) { v[j] = (bf16_t)w0[j]; v[4+j] = (bf16_t)w1[j]; }
        Wf[kk][tl] = v;
      }
    }

    __shared__ float red[4][2][64][4];   // [wave][tile][lane][reg] = 8KB

    const size_t half = (size_t)BT_TOT * N_H;

    for (int t = 0; t < T_STEPS; ++t) {
      // prefetch step-t inputs (read-only, cached normally)
      f32x2 fv = *(const f32x2*)(fs    + ((size_t)bt * T_STEPS       + t) * N_H + n0);
      f32x2 ev = *(const f32x2*)(noise + ((size_t)bt * (T_STEPS + 1) + t) * N_H + n0);

      // wait for the 64 producers of this bt-group: flags >= t+1 (relaxed polls,
      // device-scope -> served fresh from L3; no acquire fence needed since the
      // data loads below also bypass L1/L2)
      if (wave == 0) {
        const int fi = (bti << 6) | lane;
        int cnt = 0;
        for (;;) {
          int v = __hip_atomic_load(&flags[fi], __ATOMIC_RELAXED,
                                    __HIP_MEMORY_SCOPE_AGENT);
          if (__all(v >= t + 1)) break;
          if (++cnt > (1 << 18)) break;    // safety valve: wrong > hung
          __builtin_amdgcn_s_sleep(2);
        }
      }
      __syncthreads();

      // ---- A-fragments: 16 in-flight device-scope 16B loads from L3 ----
      // A[row=lane&15][k=quad*8+j] = r[bt0+l15][kw0 + kk*32 + quad*8 + j]
      const bf16_t* rsrc  = rbuf + (size_t)(t & 1) * half;
      const bf16_t* abase = rsrc + (size_t)(bt0 + l15) * N_H + (kw0 + quad * 8);
      bf16x8 af[16];
#define LOADA(I, OFFS) \
      asm volatile("global_load_dwordx4 %0, %1, off offset:" OFFS " sc0 sc1" \
                   : "=v"(af[I]) : "v"(abase) : "memory")
      LOADA(0,"0");    LOADA(1,"64");   LOADA(2,"128");  LOADA(3,"192");
      LOADA(4,"256");  LOADA(5,"320");  LOADA(6,"384");  LOADA(7,"448");
      LOADA(8,"512");  LOADA(9,"576");  LOADA(10,"640"); LOADA(11,"704");
      LOADA(12,"768"); LOADA(13,"832"); LOADA(14,"896"); LOADA(15,"960");
#undef LOADA
      asm volatile("s_waitcnt vmcnt(0)" ::: "memory");
      __builtin_amdgcn_sched_barrier(0);   // rule #18: keep MFMAs below the wait

      f32x4 acc0 = {0.f,0.f,0.f,0.f}, acc1 = {0.f,0.f,0.f,0.f};
#pragma unroll
      for (int kk = 0; kk < 16; ++kk) {
        acc0 = __builtin_amdgcn_mfma_f32_16x16x32_bf16(af[kk], Wf[kk][0], acc0, 0, 0, 0);
        acc1 = __builtin_amdgcn_mfma_f32_16x16x32_bf16(af[kk], Wf[kk][1], acc1, 0, 0, 0);
      }

      // ---- cross-wave K reduction via LDS ----
      *reinterpret_cast<f32x4*>(&red[wave][0][lane][0]) = acc0;
      *reinterpret_cast<f32x4*>(&red[wave][1][lane][0]) = acc1;
      __syncthreads();

      // C/D layout: col = lane&15 (= m within tile), row = quad*4 + reg (= bt)
      float rec0 = red[0][tile][srcl][reg]     + red[1][tile][srcl][reg]
                 + red[2][tile][srcl][reg]     + red[3][tile][srcl][reg];
      float rec1 = red[0][tile][srcl + 1][reg] + red[1][tile][srcl + 1][reg]
                 + red[2][tile][srcl + 1][reg] + red[3][tile][srcl + 1][reg];

      float du0 = (-uA + fv.x + rec0 + bv.x + ev.x) * ti0;
      float du1 = (-uB + fv.y + rec1 + bv.y + ev.y) * ti1;
      float un0 = fminf(fmaxf(uA + du0 * 0.001f, -5.0f), 5.0f);
      float un1 = fminf(fmaxf(uB + du1 * 0.001f, -5.0f), 5.0f);
      uA = un0; uB = un1;

      // r_{t+1}: single packed dword, device-scope -> L3
      {
        bf16_t* rdst = rbuf + (size_t)((t + 1) & 1) * half;
        union { bf16_t h[2]; unsigned int w; } rp;
        rp.h[0] = (bf16_t)fmaxf(un0, 0.0f);
        rp.h[1] = (bf16_t)fmaxf(un1, 0.0f);
        __hip_atomic_store((unsigned int*)(rdst + (size_t)bt * N_H + n0), rp.w,
                           __ATOMIC_RELAXED, __HIP_MEMORY_SCOPE_AGENT);
      }

      // release: my r_t reads + r_{t+1} store acked, then relaxed flag store.
      // (barrier also re-protects `red` for the next iteration)
      asm volatile("s_waitcnt vmcnt(0)" ::: "memory");
      __syncthreads();
      if (tid == 0)
        __hip_atomic_store(&flags[g], t + 2, __ATOMIC_RELAXED,
                           __HIP_MEMORY_SCOPE_AGENT);

      // history writes AFTER the flag: off the notification critical path,
      // they drain while everyone polls / loads the next r.
      const size_t o = ((size_t)bt * T_STEPS + t) * N_H + n0;
      f32x2 uo; uo.x = un0; uo.y = un1;
      f32x2 dd; dd.x = du0; dd.y = du1;
      *(f32x2*)(u_hist + o)  = uo;
      *(f32x2*)(du_hist + o) = dd;
    }

    // eta_final = noise[:, :, T]
    f32x2 ef = *(const f32x2*)(noise + ((size_t)bt * (T_STEPS + 1) + T_STEPS) * N_H + n0);
    *(f32x2*)(eta_out + (size_t)bt * N_H + n0) = ef;
}

extern "C" void kernel_launch(void* const* d_in, const int* in_sizes, int n_in,
                              void* d_out, int out_size, void* d_ws, size_t ws_size,
                              hipStream_t stream) {
    const float* u0    = (const float*)d_in[0];
    const float* fs    = (const float*)d_in[1];
    const float* noise = (const float*)d_in[2];
    const float* Wrec  = (const float*)d_in[3];
    const float* bias  = (const float*)d_in[4];
    float* out = (float*)d_out;

    // d_ws layout: [0,4096) flags (256 ints used), [4096, +512KB) r double buffer
    int*    flags = (int*)d_ws;
    bf16_t* rbuf  = (bf16_t*)((char*)d_ws + 4096);

    hipMemsetAsync(d_ws, 0, 4096, stream);   // flags must start at 0 every call

    rnn_persistent<<<dim3(256), dim3(256), 0, stream>>>(
        u0, fs, noise, Wrec, bias, out, rbuf, flags);
}